// Round 6
// baseline (592.490 us; speedup 1.0000x reference)
//
#include <hip/hip_runtime.h>
#include <hip/hip_bf16.h>

// GAT: N=50000, E=850000, HID=128, HEADS=8, DH=16, LAYERS=2.
// R6: keep head-sliced h (L2-resident per XCD, proven by R5 FETCH drop) but
//     precompute edge weights once (wprep: lane = edge x slice), so aggregate
//     is pure gather+fma. Alphas in interleaved [node][8] layout.

typedef __attribute__((ext_vector_type(8))) short short8;   // 8 bf16 = 4 VGPRs
typedef __attribute__((ext_vector_type(4))) float floatx4;

__device__ __forceinline__ unsigned f2u(float f) { return __float_as_uint(f); }
__device__ __forceinline__ float u2f(unsigned u) { return __uint_as_float(u); }
__device__ __forceinline__ unsigned short f2bf_rne(float x) {
    unsigned u = f2u(x);
    unsigned r = (u + 0x7FFF + ((u >> 16) & 1)) >> 16;
    return (unsigned short)r;
}
__device__ __forceinline__ float bf2f(unsigned short b) { return u2f(((unsigned)b) << 16); }

// ---------------- CSR build ----------------

__global__ void hist_kernel(const int* __restrict__ row, int* __restrict__ deg, int E) {
    int e = blockIdx.x * 256 + threadIdx.x;
    if (e < E) atomicAdd(&deg[row[e]], 1);
}

__global__ void blocksum_kernel(const int* __restrict__ deg, int* __restrict__ bsum, int n) {
    __shared__ int sd[512];
    int t = threadIdx.x;
    int idx = blockIdx.x * 512 + t;
    sd[t] = (idx < n) ? deg[idx] : 0;
    __syncthreads();
    for (int off = 256; off; off >>= 1) {
        if (t < off) sd[t] += sd[t + off];
        __syncthreads();
    }
    if (t == 0) bsum[blockIdx.x] = sd[0];
}

__global__ void scanbsum_kernel(const int* __restrict__ bsum, int* __restrict__ boff,
                                int nb, int* __restrict__ rowptr, int n) {
    __shared__ int sd[128];
    int t = threadIdx.x;
    int v = (t < nb) ? bsum[t] : 0;
    sd[t] = v;
    __syncthreads();
    for (int off = 1; off < 128; off <<= 1) {
        int add = (t >= off) ? sd[t - off] : 0;
        __syncthreads();
        sd[t] += add;
        __syncthreads();
    }
    if (t < nb) boff[t] = sd[t] - v;
    if (t == nb - 1) rowptr[n] = sd[t];
}

__global__ void scanfinal_kernel(const int* __restrict__ deg, const int* __restrict__ boff,
                                 int* __restrict__ rowptr, int* __restrict__ cursor, int n) {
    __shared__ int sd[512];
    int t = threadIdx.x;
    int idx = blockIdx.x * 512 + t;
    int v = (idx < n) ? deg[idx] : 0;
    sd[t] = v;
    __syncthreads();
    for (int off = 1; off < 512; off <<= 1) {
        int add = (t >= off) ? sd[t - off] : 0;
        __syncthreads();
        sd[t] += add;
        __syncthreads();
    }
    if (idx < n) {
        int excl = sd[t] - v + boff[blockIdx.x];
        rowptr[idx] = excl;
        cursor[idx] = excl;
    }
}

__global__ void scatter_kernel(const int* __restrict__ row, const int* __restrict__ colv,
                               const float* __restrict__ ev, int* __restrict__ cursor,
                               int2* __restrict__ csr, int E) {
    int e = blockIdx.x * 256 + threadIdx.x;
    if (e < E) {
        int r = row[e];
        int slot = atomicAdd(&cursor[r], 1);
        csr[slot] = make_int2(colv[e], __float_as_int(ev[e]));
    }
}

// ---------------- W pack: fp32 -> split-bf16 B-fragment layout ----------------

__global__ void pack_kernel(const float* __restrict__ encW, const float* __restrict__ Wstack,
                            short8* __restrict__ Wh, short8* __restrict__ Wl) {
    int idx = blockIdx.x * 256 + threadIdx.x;
    if (idx >= 3 * 2048) return;
    int mat = idx >> 11;
    int r = idx & 2047;
    int lane = r & 63;
    int tile = r >> 6;            // ct*4 + kt
    int ct = tile >> 2, kt = tile & 3;
    int ncol = ct * 16 + (lane & 15);
    int k0 = kt * 32 + ((lane >> 4) * 8);
    short8 hv, lv;
#pragma unroll
    for (int j = 0; j < 8; ++j) {
        int k = k0 + j;
        float w = (mat == 0)
            ? encW[k * 128 + ncol]
            : Wstack[(mat - 1) * 16384 + (ncol >> 4) * 2048 + k * 16 + (ncol & 15)];
        unsigned u = f2u(w);
        hv[j] = (short)(u >> 16);
        float hf = u2f(u & 0xFFFF0000u);
        float l = w - hf;
        lv[j] = (short)(f2u(l) >> 16);
    }
    Wh[idx] = hv;
    Wl[idx] = lv;
}

// ---------------- MFMA GEMM ----------------
// flags: bit0 = add bias, bit1 = alpha epilogue ([node*8+head] layout),
//        bit2 = store C as bf16 in SLICED layout h[s][node][16].

__global__ __launch_bounds__(256) void
gemm_mfma(const float* __restrict__ A, const short8* __restrict__ Bh,
          const short8* __restrict__ Bl, const float* __restrict__ bias,
          const float* __restrict__ avec, float* __restrict__ Cf,
          unsigned short* __restrict__ Cbf,
          float* __restrict__ asrc, float* __restrict__ adst, int n, int flags) {
    int wave = threadIdx.x >> 6;
    int lane = threadIdx.x & 63;
    int q = lane >> 4;
    int col = lane & 15;
    int n0w = blockIdx.x * 64 + wave * 16;

    int arow = min(n0w + col, n - 1);
    const float* Arow = A + (size_t)arow * 128;
    int kb = q * 8;
    short8 Ah[4], Al[4];
#pragma unroll
    for (int kt = 0; kt < 4; ++kt) {
        float4 f0 = *(const float4*)(Arow + kt * 32 + kb);
        float4 f1 = *(const float4*)(Arow + kt * 32 + kb + 4);
        float fv[8] = {f0.x, f0.y, f0.z, f0.w, f1.x, f1.y, f1.z, f1.w};
#pragma unroll
        for (int j = 0; j < 8; ++j) {
            unsigned u = f2u(fv[j]);
            Ah[kt][j] = (short)(u >> 16);
            float hf = u2f(u & 0xFFFF0000u);
            float l = fv[j] - hf;
            Al[kt][j] = (short)(f2u(l) >> 16);
        }
    }

    int nbase = n0w + q * 4;
#pragma unroll
    for (int ct = 0; ct < 8; ++ct) {
        short8 bh[4], bl[4];
#pragma unroll
        for (int kt = 0; kt < 4; ++kt) {
            bh[kt] = Bh[(ct * 4 + kt) * 64 + lane];
            bl[kt] = Bl[(ct * 4 + kt) * 64 + lane];
        }
        float bv = (flags & 1) ? bias[ct * 16 + col] : 0.f;
        floatx4 acc = {bv, bv, bv, bv};
#pragma unroll
        for (int kt = 0; kt < 4; ++kt) {
            acc = __builtin_amdgcn_mfma_f32_16x16x32_bf16(Ah[kt], bh[kt], acc, 0, 0, 0);
            acc = __builtin_amdgcn_mfma_f32_16x16x32_bf16(Al[kt], bh[kt], acc, 0, 0, 0);
            acc = __builtin_amdgcn_mfma_f32_16x16x32_bf16(Ah[kt], bl[kt], acc, 0, 0, 0);
        }
#pragma unroll
        for (int reg = 0; reg < 4; ++reg) {
            int node = nbase + reg;
            if (node < n) {
                if (flags & 4)
                    Cbf[(size_t)ct * n * 16 + (size_t)node * 16 + col] = f2bf_rne(acc[reg]);
                else
                    Cf[(size_t)node * 128 + ct * 16 + col] = acc[reg];
            }
        }
        if (flags & 2) {
            float a_s = avec[ct * 32 + col];
            float a_d = avec[ct * 32 + 16 + col];
#pragma unroll
            for (int reg = 0; reg < 4; ++reg) {
                float ps = acc[reg] * a_s;
                float pd = acc[reg] * a_d;
#pragma unroll
                for (int off = 8; off; off >>= 1) {
                    ps += __shfl_down(ps, off, 16);
                    pd += __shfl_down(pd, off, 16);
                }
                int node = nbase + reg;
                if (col == 0 && node < n) {
                    asrc[(size_t)node * 8 + ct] = ps;
                    adst[(size_t)node * 8 + ct] = pd;
                }
            }
        }
    }
}

// ---------------- wprep: per-(edge,slice) weight, computed once ----------------
// Wave per node; lane = e8*8 + s (8 edges x 8 slices). Writes ew[s][j] = (col, w).

__global__ __launch_bounds__(256) void
wprep_kernel(const int* __restrict__ rowptr, const int2* __restrict__ csr,
             const float* __restrict__ asrc, const float* __restrict__ adst,
             int2* __restrict__ ew, int E, int n) {
    int wave = threadIdx.x >> 6;
    int lane = threadIdx.x & 63;
    int nd = blockIdx.x * 4 + wave;
    if (nd >= n) return;
    int e8 = lane >> 3, s = lane & 7;
    float as = asrc[(size_t)nd * 8 + s];
    int s0 = rowptr[nd], e0 = rowptr[nd + 1];
    for (int j = s0 + e8; j < e0; j += 8) {
        int2 cv = csr[j];
        float ad = adst[(size_t)cv.x * 8 + s];
        float lg = __int_as_float(cv.y) * (as + ad);
        lg = lg > 0.f ? lg : 0.2f * lg;
        float w = __expf(lg);
        ew[(size_t)s * E + j] = make_int2(cv.x, __float_as_int(w));
    }
}

// ---------------- aggregate: head-sliced, pure gather+fma ----------------
// blockIdx = nodeChunk*8 + slice; wave w -> node nodeChunk*4 + w.
// Lane = e4*16 + f. Slice h table (1.6MB) is per-XCD-L2 resident when the
// round-robin block->XCD mapping holds (perf-only assumption).

__global__ __launch_bounds__(256) void
aggregate_kernel(const int* __restrict__ rowptr, const int2* __restrict__ ew,
                 const unsigned short* __restrict__ hsl,
                 const float* __restrict__ resid, float* __restrict__ out,
                 int mode, int E, int n) {
    int wave = threadIdx.x >> 6;
    int lane = threadIdx.x & 63;
    int slice = blockIdx.x & 7;
    int nd = (blockIdx.x >> 3) * 4 + wave;
    if (nd >= n) return;
    int e4 = lane >> 4, f = lane & 15;

    const unsigned short* hs = hsl + (size_t)slice * n * 16;
    const int2* ews = ew + (size_t)slice * E;
    int s0 = rowptr[nd], e0 = rowptr[nd + 1];

    float acc = 0.f, wsum = 0.f;
    int j = s0 + e4;
    for (; j + 8 <= e0; j += 8) {
        int2 cw1 = ews[j];
        int2 cw2 = ews[j + 4];
        unsigned short h1 = hs[(size_t)cw1.x * 16 + f];
        unsigned short h2 = hs[(size_t)cw2.x * 16 + f];
        float w1 = __int_as_float(cw1.y);
        float w2 = __int_as_float(cw2.y);
        acc += w1 * bf2f(h1) + w2 * bf2f(h2);
        wsum += w1 + w2;
    }
    for (; j < e0; j += 4) {
        int2 cw = ews[j];
        unsigned short hv = hs[(size_t)cw.x * 16 + f];
        float w = __int_as_float(cw.y);
        acc += w * bf2f(hv);
        wsum += w;
    }
    acc += __shfl_xor(acc, 16, 64);
    acc += __shfl_xor(acc, 32, 64);
    wsum += __shfl_xor(wsum, 16, 64);
    wsum += __shfl_xor(wsum, 32, 64);

    if (lane < 16) {
        float o = acc / wsum;   // self-loop guarantees wsum > 0
        size_t oi = (size_t)nd * 128 + slice * 16 + f;
        if (mode == 0) {
            o = o > 0.f ? o : expm1f(o);
            out[oi] = o;
        } else {
            out[oi] = o + resid[oi];
        }
    }
}

// ---------------- launch ----------------

extern "C" void kernel_launch(void* const* d_in, const int* in_sizes, int n_in,
                              void* d_out, int out_size, void* d_ws, size_t ws_size,
                              hipStream_t stream) {
    const int N = in_sizes[0] / 128;
    const int E = in_sizes[2];

    const float* x      = (const float*)d_in[0];
    const int*   eidx   = (const int*)d_in[1];
    const float* ev     = (const float*)d_in[2];
    const float* encW   = (const float*)d_in[3];
    const float* encb   = (const float*)d_in[4];
    const float* Wstack = (const float*)d_in[5];
    const float* astack = (const float*)d_in[6];
    float* out = (float*)d_out;

    const int* row = eidx;
    const int* colv = eidx + E;

    char* p = (char*)d_ws;
    float* xc   = (float*)p; p += (size_t)N * 128 * 4;
    float* xcB  = (float*)p; p += (size_t)N * 128 * 4;
    unsigned short* hsl = (unsigned short*)p; p += (size_t)N * 128 * 2;
    float* asrc = (float*)p; p += (size_t)N * 8 * 4;
    float* adst = (float*)p; p += (size_t)N * 8 * 4;
    short8* Wh  = (short8*)p; p += 3 * 2048 * 16;
    short8* Wl  = (short8*)p; p += 3 * 2048 * 16;
    int* rowptr = (int*)p;   p += (size_t)(N + 1) * 4;
    int* cursor = (int*)p;   p += (size_t)N * 4;
    int* deg    = (int*)p;   p += (size_t)N * 4;
    int* bsum   = (int*)p;   p += 128 * 4;
    int* boff   = (int*)p;   p += 128 * 4;
    int2* csr   = (int2*)p;  p += (size_t)E * 8;
    int2* ew    = (int2*)p;  p += (size_t)E * 8 * 8;   // 8 slices x E

    const int NB = (N + 511) / 512;
    const int GB = (N + 63) / 64;
    const int WB = (N + 3) / 4;         // wprep blocks
    const int AB = ((N + 3) / 4) * 8;   // aggregate blocks

    // --- CSR build ---
    hipMemsetAsync(deg, 0, (size_t)N * 4, stream);
    hist_kernel<<<(E + 255) / 256, 256, 0, stream>>>(row, deg, E);
    blocksum_kernel<<<NB, 512, 0, stream>>>(deg, bsum, N);
    scanbsum_kernel<<<1, 128, 0, stream>>>(bsum, boff, NB, rowptr, N);
    scanfinal_kernel<<<NB, 512, 0, stream>>>(deg, boff, rowptr, cursor, N);
    scatter_kernel<<<(E + 255) / 256, 256, 0, stream>>>(row, colv, ev, cursor, csr, E);

    // --- pack weights ---
    pack_kernel<<<24, 256, 0, stream>>>(encW, Wstack, Wh, Wl);

    // --- encoder: xc = x @ encW + b (fp32 full layout) ---
    gemm_mfma<<<GB, 256, 0, stream>>>(x, Wh, Wl, encb, nullptr, xc, nullptr,
                                      nullptr, nullptr, N, 1);

    // --- layer 0 ---
    gemm_mfma<<<GB, 256, 0, stream>>>(xc, Wh + 2048, Wl + 2048, nullptr, astack,
                                      nullptr, hsl, asrc, adst, N, 2 | 4);
    wprep_kernel<<<WB, 256, 0, stream>>>(rowptr, csr, asrc, adst, ew, E, N);
    aggregate_kernel<<<AB, 256, 0, stream>>>(rowptr, ew, hsl, nullptr, xcB, 0, E, N);

    // --- layer 1 ---
    gemm_mfma<<<GB, 256, 0, stream>>>(xcB, Wh + 4096, Wl + 4096, nullptr, astack + 256,
                                      nullptr, hsl, asrc, adst, N, 2 | 4);
    wprep_kernel<<<WB, 256, 0, stream>>>(rowptr, csr, asrc, adst, ew, E, N);
    aggregate_kernel<<<AB, 256, 0, stream>>>(rowptr, ew, hsl, xcB, out, 1, E, N);
}

// Round 7
// 402.752 us; speedup vs baseline: 1.4711x; 1.4711x over previous
//
#include <hip/hip_runtime.h>
#include <hip/hip_bf16.h>

// GAT: N=50000, E=850000, HID=128, HEADS=8, DH=16, LAYERS=2.
// R7: aggregate = wave per (16 nodes x 1 slice); 4 lanes/node each owning 4
//     features (ushort4 h loads), in-line edge weights (4x redundant exp),
//     no cross-lane reduction, no LDS. Slice = blockIdx&7 pins slice->XCD.
//     Alphas in plane layout [slice][node]. wprep/ew removed.

typedef __attribute__((ext_vector_type(8))) short short8;   // 8 bf16 = 4 VGPRs
typedef __attribute__((ext_vector_type(4))) float floatx4;

__device__ __forceinline__ unsigned f2u(float f) { return __float_as_uint(f); }
__device__ __forceinline__ float u2f(unsigned u) { return __uint_as_float(u); }
__device__ __forceinline__ unsigned short f2bf_rne(float x) {
    unsigned u = f2u(x);
    unsigned r = (u + 0x7FFF + ((u >> 16) & 1)) >> 16;
    return (unsigned short)r;
}
__device__ __forceinline__ float bf2f(unsigned short b) { return u2f(((unsigned)b) << 16); }

// ---------------- CSR build ----------------

__global__ void hist_kernel(const int* __restrict__ row, int* __restrict__ deg, int E) {
    int e = blockIdx.x * 256 + threadIdx.x;
    if (e < E) atomicAdd(&deg[row[e]], 1);
}

__global__ void blocksum_kernel(const int* __restrict__ deg, int* __restrict__ bsum, int n) {
    __shared__ int sd[512];
    int t = threadIdx.x;
    int idx = blockIdx.x * 512 + t;
    sd[t] = (idx < n) ? deg[idx] : 0;
    __syncthreads();
    for (int off = 256; off; off >>= 1) {
        if (t < off) sd[t] += sd[t + off];
        __syncthreads();
    }
    if (t == 0) bsum[blockIdx.x] = sd[0];
}

__global__ void scanbsum_kernel(const int* __restrict__ bsum, int* __restrict__ boff,
                                int nb, int* __restrict__ rowptr, int n) {
    __shared__ int sd[128];
    int t = threadIdx.x;
    int v = (t < nb) ? bsum[t] : 0;
    sd[t] = v;
    __syncthreads();
    for (int off = 1; off < 128; off <<= 1) {
        int add = (t >= off) ? sd[t - off] : 0;
        __syncthreads();
        sd[t] += add;
        __syncthreads();
    }
    if (t < nb) boff[t] = sd[t] - v;
    if (t == nb - 1) rowptr[n] = sd[t];
}

__global__ void scanfinal_kernel(const int* __restrict__ deg, const int* __restrict__ boff,
                                 int* __restrict__ rowptr, int* __restrict__ cursor, int n) {
    __shared__ int sd[512];
    int t = threadIdx.x;
    int idx = blockIdx.x * 512 + t;
    int v = (idx < n) ? deg[idx] : 0;
    sd[t] = v;
    __syncthreads();
    for (int off = 1; off < 512; off <<= 1) {
        int add = (t >= off) ? sd[t - off] : 0;
        __syncthreads();
        sd[t] += add;
        __syncthreads();
    }
    if (idx < n) {
        int excl = sd[t] - v + boff[blockIdx.x];
        rowptr[idx] = excl;
        cursor[idx] = excl;
    }
}

__global__ void scatter_kernel(const int* __restrict__ row, const int* __restrict__ colv,
                               const float* __restrict__ ev, int* __restrict__ cursor,
                               int2* __restrict__ csr, int E) {
    int e = blockIdx.x * 256 + threadIdx.x;
    if (e < E) {
        int r = row[e];
        int slot = atomicAdd(&cursor[r], 1);
        csr[slot] = make_int2(colv[e], __float_as_int(ev[e]));
    }
}

// ---------------- W pack: fp32 -> split-bf16 B-fragment layout ----------------

__global__ void pack_kernel(const float* __restrict__ encW, const float* __restrict__ Wstack,
                            short8* __restrict__ Wh, short8* __restrict__ Wl) {
    int idx = blockIdx.x * 256 + threadIdx.x;
    if (idx >= 3 * 2048) return;
    int mat = idx >> 11;
    int r = idx & 2047;
    int lane = r & 63;
    int tile = r >> 6;            // ct*4 + kt
    int ct = tile >> 2, kt = tile & 3;
    int ncol = ct * 16 + (lane & 15);
    int k0 = kt * 32 + ((lane >> 4) * 8);
    short8 hv, lv;
#pragma unroll
    for (int j = 0; j < 8; ++j) {
        int k = k0 + j;
        float w = (mat == 0)
            ? encW[k * 128 + ncol]
            : Wstack[(mat - 1) * 16384 + (ncol >> 4) * 2048 + k * 16 + (ncol & 15)];
        unsigned u = f2u(w);
        hv[j] = (short)(u >> 16);
        float hf = u2f(u & 0xFFFF0000u);
        float l = w - hf;
        lv[j] = (short)(f2u(l) >> 16);
    }
    Wh[idx] = hv;
    Wl[idx] = lv;
}

// ---------------- MFMA GEMM ----------------
// flags: bit0 = add bias, bit1 = alpha epilogue (PLANE layout [head][node]),
//        bit2 = store C as bf16 in SLICED layout h[s][node][16].

__global__ __launch_bounds__(256) void
gemm_mfma(const float* __restrict__ A, const short8* __restrict__ Bh,
          const short8* __restrict__ Bl, const float* __restrict__ bias,
          const float* __restrict__ avec, float* __restrict__ Cf,
          unsigned short* __restrict__ Cbf,
          float* __restrict__ asrc, float* __restrict__ adst, int n, int flags) {
    int wave = threadIdx.x >> 6;
    int lane = threadIdx.x & 63;
    int q = lane >> 4;
    int col = lane & 15;
    int n0w = blockIdx.x * 64 + wave * 16;

    int arow = min(n0w + col, n - 1);
    const float* Arow = A + (size_t)arow * 128;
    int kb = q * 8;
    short8 Ah[4], Al[4];
#pragma unroll
    for (int kt = 0; kt < 4; ++kt) {
        float4 f0 = *(const float4*)(Arow + kt * 32 + kb);
        float4 f1 = *(const float4*)(Arow + kt * 32 + kb + 4);
        float fv[8] = {f0.x, f0.y, f0.z, f0.w, f1.x, f1.y, f1.z, f1.w};
#pragma unroll
        for (int j = 0; j < 8; ++j) {
            unsigned u = f2u(fv[j]);
            Ah[kt][j] = (short)(u >> 16);
            float hf = u2f(u & 0xFFFF0000u);
            float l = fv[j] - hf;
            Al[kt][j] = (short)(f2u(l) >> 16);
        }
    }

    int nbase = n0w + q * 4;
#pragma unroll
    for (int ct = 0; ct < 8; ++ct) {
        short8 bh[4], bl[4];
#pragma unroll
        for (int kt = 0; kt < 4; ++kt) {
            bh[kt] = Bh[(ct * 4 + kt) * 64 + lane];
            bl[kt] = Bl[(ct * 4 + kt) * 64 + lane];
        }
        float bv = (flags & 1) ? bias[ct * 16 + col] : 0.f;
        floatx4 acc = {bv, bv, bv, bv};
#pragma unroll
        for (int kt = 0; kt < 4; ++kt) {
            acc = __builtin_amdgcn_mfma_f32_16x16x32_bf16(Ah[kt], bh[kt], acc, 0, 0, 0);
            acc = __builtin_amdgcn_mfma_f32_16x16x32_bf16(Al[kt], bh[kt], acc, 0, 0, 0);
            acc = __builtin_amdgcn_mfma_f32_16x16x32_bf16(Ah[kt], bl[kt], acc, 0, 0, 0);
        }
#pragma unroll
        for (int reg = 0; reg < 4; ++reg) {
            int node = nbase + reg;
            if (node < n) {
                if (flags & 4)
                    Cbf[(size_t)ct * n * 16 + (size_t)node * 16 + col] = f2bf_rne(acc[reg]);
                else
                    Cf[(size_t)node * 128 + ct * 16 + col] = acc[reg];
            }
        }
        if (flags & 2) {
            float a_s = avec[ct * 32 + col];
            float a_d = avec[ct * 32 + 16 + col];
#pragma unroll
            for (int reg = 0; reg < 4; ++reg) {
                float ps = acc[reg] * a_s;
                float pd = acc[reg] * a_d;
#pragma unroll
                for (int off = 8; off; off >>= 1) {
                    ps += __shfl_down(ps, off, 16);
                    pd += __shfl_down(pd, off, 16);
                }
                int node = nbase + reg;
                if (col == 0 && node < n) {
                    asrc[(size_t)ct * n + node] = ps;
                    adst[(size_t)ct * n + node] = pd;
                }
            }
        }
    }
}

// ---------------- aggregate: wave = 16 nodes x 1 slice ----------------
// blockIdx = chunk*8 + slice. Block 256 = 4 waves; wave w covers nodes
// chunk*64 + w*16 .. +15. Lane = nsub*4 + q: nsub = node within wave,
// q = feature quad (features q*4..q*4+3). Each lane accumulates 4 features
// + redundant wsum; no reduction; float4 store. Per-XCD L2 working set:
// h slice 1.6MB + asrc/adst planes 0.4MB (perf-only locality assumption).

__global__ __launch_bounds__(256) void
aggregate_kernel(const int* __restrict__ rowptr, const int2* __restrict__ csr,
                 const unsigned short* __restrict__ hsl,
                 const float* __restrict__ asrc, const float* __restrict__ adst,
                 const float* __restrict__ resid, float* __restrict__ out,
                 int mode, int n) {
    int tid = threadIdx.x;
    int wave = tid >> 6, lane = tid & 63;
    int slice = blockIdx.x & 7;
    int chunk = blockIdx.x >> 3;
    int nsub = lane >> 2, q = lane & 3;
    int nd = chunk * 64 + wave * 16 + nsub;
    bool active = nd < n;
    int ndc = active ? nd : n - 1;

    const unsigned short* hs = hsl + (size_t)slice * n * 16;
    const float* adst_s = adst + (size_t)slice * n;
    float as = asrc[(size_t)slice * n + ndc];
    int s0 = rowptr[ndc], e0 = rowptr[ndc + 1];

    float a0 = 0.f, a1 = 0.f, a2 = 0.f, a3 = 0.f, wsum = 0.f;
    int j = s0;
    for (; j + 2 <= e0; j += 2) {
        int2 cv0 = csr[j];
        int2 cv1 = csr[j + 1];
        float ad0 = adst_s[cv0.x];
        float ad1 = adst_s[cv1.x];
        ushort4 h0 = *(const ushort4*)(hs + (size_t)cv0.x * 16 + q * 4);
        ushort4 h1 = *(const ushort4*)(hs + (size_t)cv1.x * 16 + q * 4);
        float lg0 = __int_as_float(cv0.y) * (as + ad0);
        float lg1 = __int_as_float(cv1.y) * (as + ad1);
        lg0 = lg0 > 0.f ? lg0 : 0.2f * lg0;
        lg1 = lg1 > 0.f ? lg1 : 0.2f * lg1;
        float w0 = __expf(lg0);
        float w1 = __expf(lg1);
        a0 += w0 * bf2f(h0.x) + w1 * bf2f(h1.x);
        a1 += w0 * bf2f(h0.y) + w1 * bf2f(h1.y);
        a2 += w0 * bf2f(h0.z) + w1 * bf2f(h1.z);
        a3 += w0 * bf2f(h0.w) + w1 * bf2f(h1.w);
        wsum += w0 + w1;
    }
    if (j < e0) {
        int2 cv = csr[j];
        float ad = adst_s[cv.x];
        ushort4 hv = *(const ushort4*)(hs + (size_t)cv.x * 16 + q * 4);
        float lg = __int_as_float(cv.y) * (as + ad);
        lg = lg > 0.f ? lg : 0.2f * lg;
        float w = __expf(lg);
        a0 += w * bf2f(hv.x);
        a1 += w * bf2f(hv.y);
        a2 += w * bf2f(hv.z);
        a3 += w * bf2f(hv.w);
        wsum += w;
    }

    if (active) {
        float inv = 1.f / wsum;   // self-loop guarantees wsum > 0
        float4 o = {a0 * inv, a1 * inv, a2 * inv, a3 * inv};
        size_t oi = (size_t)nd * 128 + slice * 16 + q * 4;
        if (mode == 0) {
            o.x = o.x > 0.f ? o.x : expm1f(o.x);
            o.y = o.y > 0.f ? o.y : expm1f(o.y);
            o.z = o.z > 0.f ? o.z : expm1f(o.z);
            o.w = o.w > 0.f ? o.w : expm1f(o.w);
        } else {
            float4 r = *(const float4*)(resid + oi);
            o.x += r.x; o.y += r.y; o.z += r.z; o.w += r.w;
        }
        *(float4*)(out + oi) = o;
    }
}

// ---------------- launch ----------------

extern "C" void kernel_launch(void* const* d_in, const int* in_sizes, int n_in,
                              void* d_out, int out_size, void* d_ws, size_t ws_size,
                              hipStream_t stream) {
    const int N = in_sizes[0] / 128;
    const int E = in_sizes[2];

    const float* x      = (const float*)d_in[0];
    const int*   eidx   = (const int*)d_in[1];
    const float* ev     = (const float*)d_in[2];
    const float* encW   = (const float*)d_in[3];
    const float* encb   = (const float*)d_in[4];
    const float* Wstack = (const float*)d_in[5];
    const float* astack = (const float*)d_in[6];
    float* out = (float*)d_out;

    const int* row = eidx;
    const int* colv = eidx + E;

    char* p = (char*)d_ws;
    float* xc   = (float*)p; p += (size_t)N * 128 * 4;
    float* xcB  = (float*)p; p += (size_t)N * 128 * 4;
    unsigned short* hsl = (unsigned short*)p; p += (size_t)N * 128 * 2;
    float* asrc = (float*)p; p += (size_t)N * 8 * 4;
    float* adst = (float*)p; p += (size_t)N * 8 * 4;
    short8* Wh  = (short8*)p; p += 3 * 2048 * 16;
    short8* Wl  = (short8*)p; p += 3 * 2048 * 16;
    int* rowptr = (int*)p;   p += (size_t)(N + 1) * 4;
    int* cursor = (int*)p;   p += (size_t)N * 4;
    int* deg    = (int*)p;   p += (size_t)N * 4;
    int* bsum   = (int*)p;   p += 128 * 4;
    int* boff   = (int*)p;   p += 128 * 4;
    int2* csr   = (int2*)p;  p += (size_t)E * 8;

    const int NB = (N + 511) / 512;
    const int GB = (N + 63) / 64;
    const int AB = ((N + 63) / 64) * 8;   // aggregate blocks: chunk*8+slice

    // --- CSR build ---
    hipMemsetAsync(deg, 0, (size_t)N * 4, stream);
    hist_kernel<<<(E + 255) / 256, 256, 0, stream>>>(row, deg, E);
    blocksum_kernel<<<NB, 512, 0, stream>>>(deg, bsum, N);
    scanbsum_kernel<<<1, 128, 0, stream>>>(bsum, boff, NB, rowptr, N);
    scanfinal_kernel<<<NB, 512, 0, stream>>>(deg, boff, rowptr, cursor, N);
    scatter_kernel<<<(E + 255) / 256, 256, 0, stream>>>(row, colv, ev, cursor, csr, E);

    // --- pack weights ---
    pack_kernel<<<24, 256, 0, stream>>>(encW, Wstack, Wh, Wl);

    // --- encoder: xc = x @ encW + b (fp32 full layout) ---
    gemm_mfma<<<GB, 256, 0, stream>>>(x, Wh, Wl, encb, nullptr, xc, nullptr,
                                      nullptr, nullptr, N, 1);

    // --- layer 0 ---
    gemm_mfma<<<GB, 256, 0, stream>>>(xc, Wh + 2048, Wl + 2048, nullptr, astack,
                                      nullptr, hsl, asrc, adst, N, 2 | 4);
    aggregate_kernel<<<AB, 256, 0, stream>>>(rowptr, csr, hsl, asrc, adst,
                                             nullptr, xcB, 0, N);

    // --- layer 1 ---
    gemm_mfma<<<GB, 256, 0, stream>>>(xcB, Wh + 4096, Wl + 4096, nullptr, astack + 256,
                                      nullptr, hsl, asrc, adst, N, 2 | 4);
    aggregate_kernel<<<AB, 256, 0, stream>>>(rowptr, csr, hsl, asrc, adst,
                                             xcB, out, 1, N);
}